// Round 1
// baseline (236.662 us; speedup 1.0000x reference)
//
#include <hip/hip_runtime.h>
#include <math.h>
#include <float.h>

// Problem constants (x: [8192,128] f32, n_images=2)
static constexpr int NN   = 8192;
static constexpr int DD   = 128;
static constexpr int PP   = 4096;           // persons
static constexpr int TILE = 128;
static constexpr int TT   = NN / TILE;      // 64 tiles per dim
static constexpr int NBLK = TT * (TT + 1) / 2; // 2080 upper-tri tile pairs
static constexpr int BK   = 32;

struct Cand { float v; unsigned idx; };

// ---- merge top-2 sets: (v1,i1,v2,i2) <- merge with (w1,j1,w2,j2) ----
__device__ __forceinline__ void merge2(float& v1, unsigned& i1, float& v2, unsigned& i2,
                                       float w1, unsigned j1, float w2, unsigned j2) {
    if (w1 > v1) {
        float nv2; unsigned ni2;
        if (v1 >= w2) { nv2 = v1; ni2 = i1; } else { nv2 = w2; ni2 = j2; }
        v1 = w1; i1 = j1; v2 = nv2; i2 = ni2;
    } else if (w1 > v2) {
        v2 = w1; i2 = j1;
    }
}

__device__ __forceinline__ void push1(float& v1, unsigned& i1, float& v2, unsigned& i2,
                                      float w, unsigned j) {
    if (w > v1) { v2 = v1; i2 = i1; v1 = w; i1 = j; }
    else if (w > v2) { v2 = w; i2 = j; }
}

// ---- kernel 1: sim_self[p] = dot(x[p], x[p+1]) in double ----
__global__ void k_simself(const float* __restrict__ x, double* __restrict__ ss) {
    int p = blockIdx.x * blockDim.x + threadIdx.x;
    if (p >= PP) return;
    const float* a = x + (size_t)p * DD;
    const float* b = a + DD;
    double s = 0.0;
    #pragma unroll 16
    for (int k = 0; k < DD; ++k) s += (double)a[k] * (double)b[k];
    ss[p] = s;
}

// ---- kernel 2: per-tile-pair top-2 of upper triangle of x x^T ----
__global__ __launch_bounds__(256) void k_top2(const float* __restrict__ x,
                                              Cand* __restrict__ cands) {
    __shared__ float As[BK][TILE + 4];
    __shared__ float Bs[BK][TILE + 4];
    __shared__ float sv1[4], sv2[4];
    __shared__ unsigned si1[4], si2[4];

    // decode linear block id -> (ti, tj), ti <= tj (row-major over upper tri)
    int rem = blockIdx.x;
    int ti = 0;
    while (rem >= TT - ti) { rem -= (TT - ti); ++ti; }
    int tj = ti + rem;

    const int tid = threadIdx.x;
    const int ti_sub = tid >> 4;   // 0..15
    const int tj_sub = tid & 15;   // 0..15

    float c[8][8];
    #pragma unroll
    for (int m = 0; m < 8; ++m)
        #pragma unroll
        for (int n = 0; n < 8; ++n) c[m][n] = 0.f;

    const float* Ag = x + (size_t)ti * TILE * DD;
    const float* Bg = x + (size_t)tj * TILE * DD;

    for (int kk = 0; kk < DD; kk += BK) {
        __syncthreads();
        // stage 128 rows x 32 cols for A and B: 1024 float4 each, 4 per thread
        #pragma unroll
        for (int s = 0; s < 4; ++s) {
            int f   = tid + 256 * s;   // 0..1023
            int row = f >> 3;          // 0..127
            int cg  = f & 7;           // 0..7
            float4 av = *(const float4*)(Ag + row * DD + kk + cg * 4);
            float4 bv = *(const float4*)(Bg + row * DD + kk + cg * 4);
            As[cg * 4 + 0][row] = av.x; As[cg * 4 + 1][row] = av.y;
            As[cg * 4 + 2][row] = av.z; As[cg * 4 + 3][row] = av.w;
            Bs[cg * 4 + 0][row] = bv.x; Bs[cg * 4 + 1][row] = bv.y;
            Bs[cg * 4 + 2][row] = bv.z; Bs[cg * 4 + 3][row] = bv.w;
        }
        __syncthreads();

        for (int k = 0; k < BK; ++k) {
            float4 a0 = *(const float4*)&As[k][ti_sub * 8];
            float4 a1 = *(const float4*)&As[k][ti_sub * 8 + 4];
            float4 b0 = *(const float4*)&Bs[k][tj_sub * 8];
            float4 b1 = *(const float4*)&Bs[k][tj_sub * 8 + 4];
            float a[8]  = {a0.x, a0.y, a0.z, a0.w, a1.x, a1.y, a1.z, a1.w};
            float bb[8] = {b0.x, b0.y, b0.z, b0.w, b1.x, b1.y, b1.z, b1.w};
            #pragma unroll
            for (int m = 0; m < 8; ++m)
                #pragma unroll
                for (int n = 0; n < 8; ++n)
                    c[m][n] = fmaf(a[m], bb[n], c[m][n]);
        }
    }

    // per-thread top-2 over valid (i<j) elements
    float v1 = -INFINITY, v2 = -INFINITY;
    unsigned i1 = 0, i2 = 0;
    int gi0 = ti * TILE + ti_sub * 8;
    int gj0 = tj * TILE + tj_sub * 8;
    #pragma unroll
    for (int m = 0; m < 8; ++m) {
        int gi = gi0 + m;
        #pragma unroll
        for (int n = 0; n < 8; ++n) {
            int gj = gj0 + n;
            if (gi < gj) {
                unsigned idx = (unsigned)(gi * NN + gj);
                push1(v1, i1, v2, i2, c[m][n], idx);
            }
        }
    }

    // wave (64-lane) shuffle reduction
    #pragma unroll
    for (int off = 32; off >= 1; off >>= 1) {
        float    w1 = __shfl_down(v1, off);
        unsigned j1 = (unsigned)__shfl_down((int)i1, off);
        float    w2 = __shfl_down(v2, off);
        unsigned j2 = (unsigned)__shfl_down((int)i2, off);
        merge2(v1, i1, v2, i2, w1, j1, w2, j2);
    }

    int lane = tid & 63, wv = tid >> 6;
    if (lane == 0) { sv1[wv] = v1; si1[wv] = i1; sv2[wv] = v2; si2[wv] = i2; }
    __syncthreads();
    if (tid == 0) {
        for (int w = 1; w < 4; ++w)
            merge2(v1, i1, v2, i2, sv1[w], si1[w], sv2[w], si2[w]);
        cands[2 * blockIdx.x]     = {v1, i1};
        cands[2 * blockIdx.x + 1] = {v2, i2};
    }
}

// ---- kernel 3: reduce candidates, recompute top-2 in double, final mean ----
__global__ __launch_bounds__(256) void k_final(const float* __restrict__ x,
                                               const double* __restrict__ ss,
                                               const Cand* __restrict__ cands,
                                               float* __restrict__ out) {
    __shared__ float sv1[4], sv2[4];
    __shared__ unsigned si1[4], si2[4];
    __shared__ double g1, g2;
    __shared__ unsigned gtopi;
    __shared__ double sacc[256];

    const int tid = threadIdx.x;
    float v1 = -INFINITY, v2 = -INFINITY;
    unsigned i1 = 0, i2 = 0;
    for (int e = tid; e < 2 * NBLK; e += 256) {
        Cand cd = cands[e];
        push1(v1, i1, v2, i2, cd.v, cd.idx);
    }
    #pragma unroll
    for (int off = 32; off >= 1; off >>= 1) {
        float    w1 = __shfl_down(v1, off);
        unsigned j1 = (unsigned)__shfl_down((int)i1, off);
        float    w2 = __shfl_down(v2, off);
        unsigned j2 = (unsigned)__shfl_down((int)i2, off);
        merge2(v1, i1, v2, i2, w1, j1, w2, j2);
    }
    int lane = tid & 63, wv = tid >> 6;
    if (lane == 0) { sv1[wv] = v1; si1[wv] = i1; sv2[wv] = v2; si2[wv] = i2; }
    __syncthreads();
    if (tid == 0) {
        for (int w = 1; w < 4; ++w)
            merge2(v1, i1, v2, i2, sv1[w], si1[w], sv2[w], si2[w]);
        // exact double recompute of the two winning dot products
        unsigned r1 = i1 / (unsigned)NN, c1 = i1 % (unsigned)NN;
        unsigned r2 = i2 / (unsigned)NN, c2 = i2 % (unsigned)NN;
        const float* pa = x + (size_t)r1 * DD;
        const float* pb = x + (size_t)c1 * DD;
        double dv1 = 0.0, dv2 = 0.0;
        for (int k = 0; k < DD; ++k) dv1 += (double)pa[k] * (double)pb[k];
        pa = x + (size_t)r2 * DD; pb = x + (size_t)c2 * DD;
        for (int k = 0; k < DD; ++k) dv2 += (double)pa[k] * (double)pb[k];
        unsigned ii1 = i1;
        if (dv2 > dv1) { double t = dv1; dv1 = dv2; dv2 = t; ii1 = i2; }
        g1 = dv1; g2 = dv2; gtopi = ii1;
    }
    __syncthreads();

    const double top1 = g1, top2 = g2;
    const unsigned topi = gtopi;
    double acc = 0.0;
    for (int p = tid; p < PP; p += 256) {
        unsigned selfidx = (unsigned)(p * NN + p + 1);
        double so = (topi == selfidx) ? top2 : top1;
        acc += so / ss[p];
    }
    sacc[tid] = acc;
    __syncthreads();
    for (int s = 128; s >= 1; s >>= 1) {
        if (tid < s) sacc[tid] += sacc[tid + s];
        __syncthreads();
    }
    if (tid == 0) out[0] = (float)(sacc[0] / (double)PP);
}

extern "C" void kernel_launch(void* const* d_in, const int* in_sizes, int n_in,
                              void* d_out, int out_size, void* d_ws, size_t ws_size,
                              hipStream_t stream) {
    (void)in_sizes; (void)n_in; (void)out_size; (void)ws_size;
    const float* x = (const float*)d_in[0];
    float* out = (float*)d_out;

    double* ss  = (double*)d_ws;                          // PP doubles
    Cand* cands = (Cand*)((char*)d_ws + PP * sizeof(double)); // 2*NBLK Cand

    k_simself<<<PP / 256, 256, 0, stream>>>(x, ss);
    k_top2<<<NBLK, 256, 0, stream>>>(x, cands);
    k_final<<<1, 256, 0, stream>>>(x, ss, cands, out);
}